// Round 8
// baseline (314.643 us; speedup 1.0000x reference)
//
#include <hip/hip_runtime.h>
#include <cstdint>
#include <cstddef>

// Problem constants
#define B_   4
#define L_   1024
#define H_   8
#define DK_  64
#define DV_  192
#define HALF_ 96
#define LOG2E_ 1.44269504088896f

typedef _Float16 half8 __attribute__((ext_vector_type(8)));
typedef _Float16 half4v __attribute__((ext_vector_type(4)));
typedef float f32x4 __attribute__((ext_vector_type(4)));

__device__ __forceinline__ void gll16(const void* g, void* lds) {
    __builtin_amdgcn_global_load_lds(
        (const __attribute__((address_space(1))) unsigned int*)g,
        (__attribute__((address_space(3))) unsigned int*)lds, 16, 0, 0);
}

// ---------------- elementwise f32 -> f16 convert (4/thread) ----------------
__global__ void k_f32_to_f16(const float* __restrict__ src, _Float16* __restrict__ dst, int n4) {
    int i = blockIdx.x * 256 + threadIdx.x;
    if (i >= n4) return;
    float4 v = ((const float4*)src)[i];
    half4v h;
    h[0] = (_Float16)v.x; h[1] = (_Float16)v.y; h[2] = (_Float16)v.z; h[3] = (_Float16)v.w;
    ((half4v*)dst)[i] = h;
}

// ---------------- transpose+convert: src[K,N] f32 -> dst[N,K] f16 ----------------
__global__ void k_transpose_f16(const float* __restrict__ src, _Float16* __restrict__ dst, int K, int N) {
    __shared__ float tile[64][65];
    int n0 = blockIdx.x << 6, k0 = blockIdx.y << 6;
    int tid = threadIdx.x;
#pragma unroll
    for (int q = 0; q < 16; ++q) {
        int e = (q << 8) + tid;
        int r = e >> 6, c = e & 63;
        tile[r][c] = src[(size_t)(k0 + r) * N + n0 + c];
    }
    __syncthreads();
#pragma unroll
    for (int q = 0; q < 16; ++q) {
        int e = (q << 8) + tid;
        int r = e >> 6, c = e & 63;
        dst[(size_t)(n0 + r) * K + k0 + c] = (_Float16)tile[c][r];
    }
}

// ---------------- bias concat bq|bk|bv -> bqkv[2560] ----------------
__global__ void k_concat_bias(const float* __restrict__ bq, const float* __restrict__ bk,
                              const float* __restrict__ bv, float* __restrict__ bqkv) {
    int i = blockIdx.x * 256 + threadIdx.x;
    if (i >= 2560) return;
    float v;
    if (i < 512) v = bq[i];
    else if (i < 1024) v = bk[i - 512];
    else v = bv[i - 1024];
    bqkv[i] = v;
}

// ---------------- trig tables: Tsin/Tcos[i*96+f] = sin/cos(i * w_f) ----------------
__global__ void k_trig(float* __restrict__ Tsin, float* __restrict__ Tcos) {
    int idx = blockIdx.x * 256 + threadIdx.x;
    if (idx >= L_ * HALF_) return;
    int i = idx / HALF_;
    int f = idx - i * HALF_;
    float w = expf(-(float)f * 0.09594104554141865f);   // ln(10000)/96
    float a = (float)i * w;
    Tsin[idx] = sinf(a);
    Tcos[idx] = cosf(a);
}

// ---------------- fp16 MFMA GEMM: C[M,TNB*nbx] = A[M,K] @ Bt[N,K]^T + bias ----------------
template<int TNB, bool OUT_F16>
__global__ __launch_bounds__(256) void k_gemm2(
    const _Float16* __restrict__ A, const _Float16* __restrict__ Bt,
    const float* __restrict__ bias, void* __restrict__ Cout,
    int M, int N, int K, int nbx)
{
    constexpr int BUFSZ = 16384 + TNB * 128;
    __shared__ char sm[2 * BUFSZ];
    const int nwg = gridDim.x;
    const int bid = blockIdx.x;
    const int sw = (bid & 7) * (nwg >> 3) + (bid >> 3);   // XCD-chunked (nwg % 8 == 0)
    const int bx = sw % nbx, by = sw / nbx;
    const int m0 = by << 7, n0 = bx * TNB;
    const int tid = threadIdx.x;
    const int lane = tid & 63, l15 = lane & 15, g = lane >> 4;
    const int w = tid >> 6;
    constexpr int AM = (TNB == 128) ? 4 : 2;
    const int wm = (TNB == 128) ? ((w >> 1) << 6) : (w << 5);
    const int wn = (TNB == 128) ? ((w & 1) << 6) : 0;

    f32x4 acc[AM][4] = {};

    auto stage = [&](int kt, int bufsel) {
        char* As = sm + bufsel * BUFSZ;
        char* Bs = As + 16384;
        const char* Ag = (const char*)A + ((size_t)m0 * K + (kt << 6)) * 2;
#pragma unroll
        for (int i2 = 0; i2 < 4; ++i2) {
            int byte = (i2 << 12) + (tid << 4);
            int row = byte >> 7, bso = byte & 127;
            gll16(Ag + (size_t)row * (K * 2) + (bso ^ ((row & 7) << 4)), As + byte);
        }
        const char* Bg = (const char*)Bt + ((size_t)n0 * K + (kt << 6)) * 2;
#pragma unroll
        for (int i2 = 0; i2 < (TNB >> 5); ++i2) {
            int byte = (i2 << 12) + (tid << 4);
            int row = byte >> 7, bso = byte & 127;
            gll16(Bg + (size_t)row * (K * 2) + (bso ^ ((row & 7) << 4)), Bs + byte);
        }
    };

    const int nk = K >> 6;
    stage(0, 0);
    __syncthreads();
    for (int kt = 0; kt < nk; ++kt) {
        const int cur = kt & 1;
        if (kt + 1 < nk) stage(kt + 1, cur ^ 1);
        const char* As = sm + cur * BUFSZ;
        const char* Bs = As + 16384;
#pragma unroll
        for (int kq = 0; kq < 2; ++kq) {
            half8 af[AM], bf[4];
#pragma unroll
            for (int a = 0; a < AM; ++a) {
                int row = wm + (a << 4) + l15;
                af[a] = *(const half8*)(As + (row << 7) + ((((kq << 2) | g) ^ (row & 7)) << 4));
            }
#pragma unroll
            for (int bj = 0; bj < 4; ++bj) {
                int row = wn + (bj << 4) + l15;
                bf[bj] = *(const half8*)(Bs + (row << 7) + ((((kq << 2) | g) ^ (row & 7)) << 4));
            }
#pragma unroll
            for (int a = 0; a < AM; ++a)
#pragma unroll
                for (int bj = 0; bj < 4; ++bj)
                    acc[a][bj] = __builtin_amdgcn_mfma_f32_16x16x32_f16(af[a], bf[bj], acc[a][bj], 0, 0, 0);
        }
        __syncthreads();
    }
#pragma unroll
    for (int a = 0; a < AM; ++a)
#pragma unroll
        for (int bj = 0; bj < 4; ++bj)
#pragma unroll
            for (int r = 0; r < 4; ++r) {
                int row = m0 + wm + (a << 4) + (g << 2) + r;
                int col = n0 + wn + (bj << 4) + l15;
                float vv = acc[a][bj][r] + (bias ? bias[col] : 0.0f);
                if (OUT_F16) ((_Float16*)Cout)[(size_t)row * N + col] = (_Float16)vv;
                else         ((float*)Cout)[(size_t)row * N + col] = vv;
            }
}

// ---------------- QVh[(bh)*1024+i][k] = f16(Qh + v_h), half8 per thread ----------------
__global__ void k_qvh(const _Float16* __restrict__ Qh, const float* __restrict__ v,
                      _Float16* __restrict__ QVh) {
    int t = blockIdx.x * 256 + threadIdx.x;     // 262144 threads
    int k8 = (t & 7) << 3, r = t >> 3;
    int i = r & 1023, h = (r >> 10) & 7, b = r >> 13;
    half8 q = *(const half8*)(Qh + ((size_t)(b << 10) + i) * 2560 + (h << 6) + k8);
    float4 v0 = *(const float4*)(v + (h << 6) + k8);
    float4 v1 = *(const float4*)(v + (h << 6) + k8 + 4);
    float vv[8] = {v0.x, v0.y, v0.z, v0.w, v1.x, v1.y, v1.z, v1.w};
    half8 o;
#pragma unroll
    for (int z = 0; z < 8; ++z) o[z] = (_Float16)((float)q[z] + vv[z]);
    ((half8*)QVh)[t] = o;
}

// ---------------- Qext build: LOG2E * [Q(64) | A'_sin(96) | A'_cos(96)], SWIZZLED ----------------
__global__ void k_qext(const _Float16* __restrict__ Qh, const _Float16* __restrict__ Gf,
                       const float* __restrict__ Tsin, const float* __restrict__ Tcos,
                       _Float16* __restrict__ Qext) {
    int t = threadIdx.x;
    int r = (blockIdx.x << 3) + (t >> 5);
    int cc = t & 31;
    int i = r & 1023, h = (r >> 10) & 7, b = r >> 13;
    half8 val;
    if (cc < 8) {
        half8 q = *(const half8*)(Qh + ((size_t)(b << 10) + i) * 2560 + (h << 6) + (cc << 3));
#pragma unroll
        for (int z = 0; z < 8; ++z) val[z] = (_Float16)((float)q[z] * LOG2E_);
    } else {
        int f = (cc < 20) ? ((cc - 8) << 3) : ((cc - 20) << 3);
        half8 g0 = *(const half8*)(Gf + (size_t)r * 192 + f);
        half8 g1 = *(const half8*)(Gf + (size_t)r * 192 + 96 + f);
        float4 s0 = *(const float4*)(Tsin + i * 96 + f);
        float4 s1 = *(const float4*)(Tsin + i * 96 + f + 4);
        float4 c0 = *(const float4*)(Tcos + i * 96 + f);
        float4 c1 = *(const float4*)(Tcos + i * 96 + f + 4);
        float sv[8] = {s0.x, s0.y, s0.z, s0.w, s1.x, s1.y, s1.z, s1.w};
        float cv[8] = {c0.x, c0.y, c0.z, c0.w, c1.x, c1.y, c1.z, c1.w};
        if (cc < 20) {
#pragma unroll
            for (int z = 0; z < 8; ++z) val[z] = (_Float16)(((float)g0[z] * cv[z] + (float)g1[z] * sv[z]) * LOG2E_);
        } else {
#pragma unroll
            for (int z = 0; z < 8; ++z) val[z] = (_Float16)(((float)g1[z] * cv[z] - (float)g0[z] * sv[z]) * LOG2E_);
        }
    }
    *(half8*)((char*)Qext + (size_t)r * 512 + ((cc ^ (r & 7)) << 4)) = val;
}

// ---------------- Kext build + bias3 = LOG2E * (u_h . K_j), SWIZZLED ----------------
__global__ void k_kext(const _Float16* __restrict__ Kh, const float* __restrict__ u,
                       const float* __restrict__ Tsin, const float* __restrict__ Tcos,
                       _Float16* __restrict__ Kext, float* __restrict__ bias3) {
    int t = threadIdx.x;
    int r = (blockIdx.x << 3) + (t >> 5);
    int cc = t & 31;
    int j = r & 1023, h = (r >> 10) & 7, b = r >> 13;
    half8 val;
    if (cc < 8) {
        val = *(const half8*)(Kh + ((size_t)(b << 10) + j) * 2560 + 512 + (h << 6) + (cc << 3));
        float4 u0 = *(const float4*)(u + (h << 6) + (cc << 3));
        float4 u1 = *(const float4*)(u + (h << 6) + (cc << 3) + 4);
        float p = (float)val[0] * u0.x + (float)val[1] * u0.y + (float)val[2] * u0.z + (float)val[3] * u0.w
                + (float)val[4] * u1.x + (float)val[5] * u1.y + (float)val[6] * u1.z + (float)val[7] * u1.w;
        p += __shfl_xor(p, 1); p += __shfl_xor(p, 2); p += __shfl_xor(p, 4);
        if (cc == 0) bias3[r] = p * LOG2E_;
    } else {
        int f = (cc < 20) ? ((cc - 8) << 3) : ((cc - 20) << 3);
        const float* T = (cc < 20) ? Tsin : Tcos;
        float4 t0 = *(const float4*)(T + j * 96 + f);
        float4 t1 = *(const float4*)(T + j * 96 + f + 4);
        float tv[8] = {t0.x, t0.y, t0.z, t0.w, t1.x, t1.y, t1.z, t1.w};
#pragma unroll
        for (int z = 0; z < 8; ++z) val[z] = (_Float16)tv[z];
    }
    *(half8*)((char*)Kext + (size_t)r * 512 + ((cc ^ (r & 7)) << 4)) = val;
}

// ---------------- V pack: Vh -> Vd[(bh*192+d)*1024 + j] f16, per-64j 128B-chunk swizzle ----------------
__global__ void k_pack_v(const _Float16* __restrict__ Vh, _Float16* __restrict__ Vd) {
    __shared__ float tile[64][65];
    int j0 = blockIdx.x << 6, d0 = blockIdx.y << 6, bh = blockIdx.z;
    int b = bh >> 3, h = bh & 7;
    int tid = threadIdx.x;
#pragma unroll
    for (int q = 0; q < 16; ++q) {
        int e = (q << 8) + tid;
        int r = e >> 6, c = e & 63;
        tile[r][c] = (float)Vh[((size_t)(b << 10) + j0 + r) * 2560 + 1024 + h * 192 + d0 + c];
    }
    __syncthreads();
#pragma unroll
    for (int q = 0; q < 2; ++q) {
        int e = (q << 8) + tid;
        int dr = e >> 3, jc = e & 7;     // dr = d offset 0..63, jc = 16B chunk (8 j)
        half8 v;
#pragma unroll
        for (int z = 0; z < 8; ++z) v[z] = (_Float16)tile[(jc << 3) + z][dr];
        *(half8*)((char*)Vd + (((size_t)bh * 192 + d0 + dr) * 1024 + j0) * 2 + ((jc ^ (dr & 7)) << 4)) = v;
    }
}

// ---------------- fused rel-pos flash attention v8 ----------------
// v5 structure with the VGPR cap removed: __launch_bounds__(512, 1).
// Empirical toolchain map: arg2>=2 -> 128-VGPR cap (spill, R4/R5/R6);
// arg2==1 -> uncapped (~232, R3/R7). An 8-wave workgroup FORCES 2 waves/SIMD
// co-residency (2x232=464 <= 512 VGPR pool/SIMD per m69), sidestepping the
// CP's refusal to pack two 4-wave blocks (R7). 256 blocks (1/CU, XCD-chunked:
// 4 bh/XCD, L2-resident K/V proven in R7 at 22.7MB fetch), 128 q-rows/block,
// KVBLK=64 double-buffered, wave = 32 rows x one j-half, slim softmax.
__global__ __launch_bounds__(512, 1) void k_attn(
    const _Float16* __restrict__ Qext, const _Float16* __restrict__ Kext,
    const _Float16* __restrict__ Vd, const float* __restrict__ bias3,
    _Float16* __restrict__ AOh)
{
    __shared__ char smem[131072];   // K0@0 K1@32K V0@64K V1@88K P@112K+w*2K

    const int bid = blockIdx.x;
    const int sw = ((bid & 7) << 5) + (bid >> 3);   // 32 blocks per XCD chunk
    const int bh = sw >> 3;
    const int i0 = (sw & 7) << 7;                   // 128 q-rows per block
    const int tid = threadIdx.x;
    const int w = tid >> 6, lane = tid & 63, l15 = lane & 15, g = lane >> 4;
    const int rowg = w & 3, jhalf = w >> 2;
    const int b = bh >> 3, h = bh & 7;

    const char* Kg = (const char*)Kext + ((size_t)bh << 10) * 512;
    const char* Vg = (const char*)Vd + (size_t)bh * 192 * 2048;
    const float* b3g = bias3 + (bh << 10);
    char* Pw = smem + 114688 + (w << 11);

    // Q fragments (swizzled global layout): rows i0 + rowg*32 + a*16 + l15
    half8 qf[2][8];
#pragma unroll
    for (int a = 0; a < 2; ++a) {
        int row = i0 + (rowg << 5) + (a << 4) + l15;
        const char* qp = (const char*)Qext + ((size_t)(bh << 10) + row) * 512;
#pragma unroll
        for (int kq = 0; kq < 8; ++kq)
            qf[a][kq] = *(const half8*)(qp + ((((kq << 2) + g) ^ (row & 7)) << 4));
    }

    f32x4 oacc[2][12] = {};
    float m_run[2][4], l_lane[2][4];
#pragma unroll
    for (int a = 0; a < 2; ++a)
#pragma unroll
        for (int r = 0; r < 4; ++r) { m_run[a][r] = -3.0e38f; l_lane[a][r] = 0.f; }

    auto stage = [&](int jt, int bufsel) {
        char* Kb = smem + bufsel * 32768;
        char* Vb = smem + 65536 + bufsel * 24576;
        const char* Ksrc = Kg + (size_t)jt * 32768;
#pragma unroll
        for (int i2 = 0; i2 < 4; ++i2) {
            int byte = (i2 << 13) + (tid << 4);
            gll16(Ksrc + byte, Kb + byte);
        }
#pragma unroll
        for (int i2 = 0; i2 < 3; ++i2) {
            int byte = (i2 << 13) + (tid << 4);
            int d = byte >> 7, c = byte & 127;
            gll16(Vg + (size_t)d * 2048 + (jt << 7) + c, Vb + byte);
        }
    };

    stage(0, 0);
    __syncthreads();

    for (int jt = 0; jt < 16; ++jt) {
        const int cur = jt & 1;
        if (jt + 1 < 16) stage(jt + 1, cur ^ 1);
        const char* Kb = smem + cur * 32768;
        const char* Vb = smem + 65536 + cur * 24576;

        // S = Qext @ Kext^T : 2 row-frags x 2 col-frags (wave's 32-col j-half)
        f32x4 s[2][2] = {};
        __builtin_amdgcn_s_setprio(1);
#pragma unroll
        for (int kq = 0; kq < 8; ++kq) {
#pragma unroll
            for (int jn = 0; jn < 2; ++jn) {
                int krow = (((jhalf << 1) + jn) << 4) + l15;
                half8 bf = *(const half8*)(Kb + (krow << 9) + ((((kq << 2) + g) ^ (krow & 7)) << 4));
                s[0][jn] = __builtin_amdgcn_mfma_f32_16x16x32_f16(qf[0][kq], bf, s[0][jn], 0, 0, 0);
                s[1][jn] = __builtin_amdgcn_mfma_f32_16x16x32_f16(qf[1][kq], bf, s[1][jn], 0, 0, 0);
            }
        }
        __builtin_amdgcn_s_setprio(0);
        // + term3 column bias
#pragma unroll
        for (int jn = 0; jn < 2; ++jn) {
            float b3 = b3g[(jt << 6) + (jhalf << 5) + (jn << 4) + l15];
#pragma unroll
            for (int a = 0; a < 2; ++a)
#pragma unroll
                for (int r = 0; r < 4; ++r) s[a][jn][r] += b3;
        }
        // defer-max online softmax (log2 domain)
        bool pass = true;
#pragma unroll
        for (int a = 0; a < 2; ++a)
#pragma unroll
            for (int jn = 0; jn < 2; ++jn)
#pragma unroll
                for (int r = 0; r < 4; ++r) pass &= (s[a][jn][r] <= m_run[a][r] + 8.0f);
        if (!__all(pass)) {
#pragma unroll
            for (int a = 0; a < 2; ++a)
#pragma unroll
                for (int r = 0; r < 4; ++r) {
                    float tm = fmaxf(s[a][0][r], s[a][1][r]);
                    tm = fmaxf(tm, __shfl_xor(tm, 1));
                    tm = fmaxf(tm, __shfl_xor(tm, 2));
                    tm = fmaxf(tm, __shfl_xor(tm, 4));
                    tm = fmaxf(tm, __shfl_xor(tm, 8));
                    float mnew = fmaxf(m_run[a][r], tm);
                    float al = exp2f(m_run[a][r] - mnew);
                    l_lane[a][r] *= al;
                    m_run[a][r] = mnew;
#pragma unroll
                    for (int dn = 0; dn < 12; ++dn) oacc[a][dn][r] *= al;
                }
        }
        // P = exp2(s-m) -> wave-private LDS [32 rows][64B], chunk swz c^=(row>>2)&3
#pragma unroll
        for (int a = 0; a < 2; ++a)
#pragma unroll
            for (int jn = 0; jn < 2; ++jn)
#pragma unroll
                for (int r = 0; r < 4; ++r) {
                    float p = exp2f(s[a][jn][r] - m_run[a][r]);
                    l_lane[a][r] += p;
                    int row = (a << 4) + (g << 2) + r;
                    int c = ((jn << 1) + (l15 >> 3)) ^ ((row >> 2) & 3);
                    *(_Float16*)(Pw + (row << 6) + (c << 4) + ((l15 & 7) << 1)) = (_Float16)p;
                }
        // P A-frags back (same wave)
        half8 pa[2];
#pragma unroll
        for (int a = 0; a < 2; ++a) {
            int row = (a << 4) + l15;
            int c = g ^ ((row >> 2) & 3);
            pa[a] = *(const half8*)(Pw + (row << 6) + (c << 4));
        }
        // O += P @ V  (16x16x32, inner = wave's 32 j)
        __builtin_amdgcn_s_setprio(1);
#pragma unroll
        for (int dn = 0; dn < 12; ++dn) {
            int d = (dn << 4) + l15;
            half8 vb = *(const half8*)(Vb + (d << 7) + ((((jhalf << 2) + g) ^ (d & 7)) << 4));
            oacc[0][dn] = __builtin_amdgcn_mfma_f32_16x16x32_f16(pa[0], vb, oacc[0][dn], 0, 0, 0);
            oacc[1][dn] = __builtin_amdgcn_mfma_f32_16x16x32_f16(pa[1], vb, oacc[1][dn], 0, 0, 0);
        }
        __builtin_amdgcn_s_setprio(0);
        __syncthreads();
    }

    // reduce l across the 16 j-lanes (per row)
    float l_run[2][4];
#pragma unroll
    for (int a = 0; a < 2; ++a)
#pragma unroll
        for (int r = 0; r < 4; ++r) {
            float l = l_lane[a][r];
            l += __shfl_xor(l, 1);
            l += __shfl_xor(l, 2);
            l += __shfl_xor(l, 4);
            l += __shfl_xor(l, 8);
            l_run[a][r] = l;
        }

    // ---- combine the two j-halves ----
    float* Cml = (float*)smem;             // [2 jhalf][128 rows][m,l]
    float* Co  = (float*)(smem + 2048);    // [128][196] f32 partial O
#pragma unroll
    for (int a = 0; a < 2; ++a)
#pragma unroll
        for (int r = 0; r < 4; ++r)
            if (l15 == 0) {
                int rowi = (rowg << 5) + (a << 4) + (g << 2) + r;
                Cml[(((jhalf << 7) + rowi) << 1) + 0] = m_run[a][r];
                Cml[(((jhalf << 7) + rowi) << 1) + 1] = l_run[a][r];
            }
    __syncthreads();
    float fs[2][4], lt[2][4];
#pragma unroll
    for (int a = 0; a < 2; ++a)
#pragma unroll
        for (int r = 0; r < 4; ++r) {
            int rowi = (rowg << 5) + (a << 4) + (g << 2) + r;
            float mo = Cml[((((1 - jhalf) << 7) + rowi) << 1) + 0];
            float lo = Cml[((((1 - jhalf) << 7) + rowi) << 1) + 1];
            float M = fmaxf(m_run[a][r], mo);
            float f0 = exp2f(m_run[a][r] - M);
            float f1 = exp2f(mo - M);
            fs[a][r] = f0;
            lt[a][r] = l_run[a][r] * f0 + lo * f1;
        }
    if (jhalf == 1) {
#pragma unroll
        for (int a = 0; a < 2; ++a)
#pragma unroll
            for (int dn = 0; dn < 12; ++dn)
#pragma unroll
                for (int r = 0; r < 4; ++r) {
                    int rowi = (rowg << 5) + (a << 4) + (g << 2) + r;
                    Co[rowi * 196 + (dn << 4) + l15] = oacc[a][dn][r] * fs[a][r];
                }
    }
    __syncthreads();
    if (jhalf == 0) {
#pragma unroll
        for (int a = 0; a < 2; ++a)
#pragma unroll
            for (int r = 0; r < 4; ++r) {
                int rowi = (rowg << 5) + (a << 4) + (g << 2) + r;
                float inv = 1.0f / lt[a][r];
#pragma unroll
                for (int dn = 0; dn < 12; ++dn) {
                    float ov = (oacc[a][dn][r] * fs[a][r] + Co[rowi * 196 + (dn << 4) + l15]) * inv;
                    AOh[((size_t)(b << 10) + i0 + rowi) * 1536 + h * 192 + (dn << 4) + l15] = (_Float16)ov;
                }
            }
    }
}

// ---------------- host launch ----------------
extern "C" void kernel_launch(void* const* d_in, const int* in_sizes, int n_in,
                              void* d_out, int out_size, void* d_ws, size_t ws_size,
                              hipStream_t stream) {
    const float* x  = (const float*)d_in[0];
    const float* Wq = (const float*)d_in[1];
    const float* bq = (const float*)d_in[2];
    const float* Wk = (const float*)d_in[3];
    const float* bk = (const float*)d_in[4];
    const float* Wv = (const float*)d_in[5];
    const float* bv = (const float*)d_in[6];
    const float* Wo = (const float*)d_in[7];
    const float* bo = (const float*)d_in[8];
    const float* We = (const float*)d_in[9];
    const float* u  = (const float*)d_in[10];
    const float* v  = (const float*)d_in[11];
    float* out = (float*)d_out;

    char* ws = (char*)d_ws;
    size_t off = 0;
    auto alloc = [&](size_t bytes) -> void* {
        void* p = ws + off;
        off += (bytes + 255) & ~(size_t)255;
        return p;
    };
    _Float16* xh    = (_Float16*)alloc((size_t)4096 * 512 * 2);
    _Float16* Weh   = (_Float16*)alloc((size_t)192 * 64 * 2);
    _Float16* Wqkvt = (_Float16*)alloc((size_t)2560 * 512 * 2);
    _Float16* Wot   = (_Float16*)alloc((size_t)512 * 1536 * 2);
    float*    bqkv  = (float*)alloc((size_t)2560 * 4);
    float*    Tsin  = (float*)alloc((size_t)1024 * 96 * 4);
    float*    Tcos  = (float*)alloc((size_t)1024 * 96 * 4);
    _Float16* QKVh  = (_Float16*)alloc((size_t)4096 * 2560 * 2);
    _Float16* QVh   = (_Float16*)alloc((size_t)32768 * 64 * 2);
    _Float16* Gf16  = (_Float16*)alloc((size_t)32768 * 192 * 2);
    _Float16* Qext  = (_Float16*)alloc((size_t)32768 * 256 * 2);
    _Float16* Kext  = (_Float16*)alloc((size_t)32768 * 256 * 2);
    float*    bias3 = (float*)alloc((size_t)32768 * 4);
    _Float16* Vd    = (_Float16*)alloc((size_t)32 * 192 * 1024 * 2);
    _Float16* AOh   = (_Float16*)alloc((size_t)4096 * 1536 * 2);
    if (off > ws_size) return;  // insufficient workspace -> clean fail

    // converts / transposes / tables
    k_f32_to_f16<<<2048, 256, 0, stream>>>(x, xh, 4096 * 512 / 4);
    k_f32_to_f16<<<12, 256, 0, stream>>>(We, Weh, 192 * 64 / 4);
    k_transpose_f16<<<dim3(8, 8), 256, 0, stream>>>(Wq, Wqkvt, 512, 512);
    k_transpose_f16<<<dim3(8, 8), 256, 0, stream>>>(Wk, Wqkvt + (size_t)512 * 512, 512, 512);
    k_transpose_f16<<<dim3(24, 8), 256, 0, stream>>>(Wv, Wqkvt + (size_t)1024 * 512, 512, 1536);
    k_transpose_f16<<<dim3(8, 24), 256, 0, stream>>>(Wo, Wot, 1536, 512);
    k_concat_bias<<<10, 256, 0, stream>>>(bq, bk, bv, bqkv);
    k_trig<<<(1024 * 96 + 255) / 256, 256, 0, stream>>>(Tsin, Tcos);

    // fused QKV projection (f16 out): [4096,2560] = xh @ Wqkvt^T + bqkv
    k_gemm2<128, true><<<640, 256, 0, stream>>>(xh, Wqkvt, bqkv, QKVh, 4096, 2560, 512, 20);

    // G = (Q + v_h) @ We^T  (f16 out)
    k_qvh<<<1024, 256, 0, stream>>>(QKVh, v, QVh);
    k_gemm2<64, true><<<768, 256, 0, stream>>>(QVh, Weh, nullptr, Gf16, 32768, 192, 64, 3);

    // extended Q / K (swizzled, LOG2E-folded) + column bias; V pack (swizzled)
    k_qext<<<4096, 256, 0, stream>>>(QKVh, Gf16, Tsin, Tcos, Qext);
    k_kext<<<4096, 256, 0, stream>>>(QKVh, u, Tsin, Tcos, Kext, bias3);
    k_pack_v<<<dim3(16, 3, 32), 256, 0, stream>>>(QKVh, Vd);

    // fused attention
    k_attn<<<256, 512, 0, stream>>>(Qext, Kext, Vd, bias3, AOh);

    // output projection -> d_out (f32)
    k_gemm2<64, false><<<256, 256, 0, stream>>>(AOh, Wot, bo, out, 4096, 512, 1536, 8);
}

// Round 9
// 185.755 us; speedup vs baseline: 1.6939x; 1.6939x over previous
//
#include <hip/hip_runtime.h>
#include <cstdint>
#include <cstddef>

// Problem constants
#define B_   4
#define L_   1024
#define H_   8
#define DK_  64
#define DV_  192
#define HALF_ 96
#define LOG2E_ 1.44269504088896f

typedef _Float16 half8 __attribute__((ext_vector_type(8)));
typedef _Float16 half4v __attribute__((ext_vector_type(4)));
typedef float f32x4 __attribute__((ext_vector_type(4)));

__device__ __forceinline__ void gll16(const void* g, void* lds) {
    __builtin_amdgcn_global_load_lds(
        (const __attribute__((address_space(1))) unsigned int*)g,
        (__attribute__((address_space(3))) unsigned int*)lds, 16, 0, 0);
}

// ---------------- elementwise f32 -> f16 convert (4/thread) ----------------
__global__ void k_f32_to_f16(const float* __restrict__ src, _Float16* __restrict__ dst, int n4) {
    int i = blockIdx.x * 256 + threadIdx.x;
    if (i >= n4) return;
    float4 v = ((const float4*)src)[i];
    half4v h;
    h[0] = (_Float16)v.x; h[1] = (_Float16)v.y; h[2] = (_Float16)v.z; h[3] = (_Float16)v.w;
    ((half4v*)dst)[i] = h;
}

// ---------------- transpose+convert: src[K,N] f32 -> dst[N,K] f16 ----------------
__global__ void k_transpose_f16(const float* __restrict__ src, _Float16* __restrict__ dst, int K, int N) {
    __shared__ float tile[64][65];
    int n0 = blockIdx.x << 6, k0 = blockIdx.y << 6;
    int tid = threadIdx.x;
#pragma unroll
    for (int q = 0; q < 16; ++q) {
        int e = (q << 8) + tid;
        int r = e >> 6, c = e & 63;
        tile[r][c] = src[(size_t)(k0 + r) * N + n0 + c];
    }
    __syncthreads();
#pragma unroll
    for (int q = 0; q < 16; ++q) {
        int e = (q << 8) + tid;
        int r = e >> 6, c = e & 63;
        dst[(size_t)(n0 + r) * K + k0 + c] = (_Float16)tile[c][r];
    }
}

// ---------------- bias concat bq|bk|bv -> bqkv[2560] ----------------
__global__ void k_concat_bias(const float* __restrict__ bq, const float* __restrict__ bk,
                              const float* __restrict__ bv, float* __restrict__ bqkv) {
    int i = blockIdx.x * 256 + threadIdx.x;
    if (i >= 2560) return;
    float v;
    if (i < 512) v = bq[i];
    else if (i < 1024) v = bk[i - 512];
    else v = bv[i - 1024];
    bqkv[i] = v;
}

// ---------------- trig tables: Tsin/Tcos[i*96+f] = sin/cos(i * w_f) ----------------
__global__ void k_trig(float* __restrict__ Tsin, float* __restrict__ Tcos) {
    int idx = blockIdx.x * 256 + threadIdx.x;
    if (idx >= L_ * HALF_) return;
    int i = idx / HALF_;
    int f = idx - i * HALF_;
    float w = expf(-(float)f * 0.09594104554141865f);   // ln(10000)/96
    float a = (float)i * w;
    Tsin[idx] = sinf(a);
    Tcos[idx] = cosf(a);
}

// ---------------- fp16 MFMA GEMM: C[M,TNB*nbx] = A[M,K] @ Bt[N,K]^T + bias ----------------
template<int TNB, bool OUT_F16>
__global__ __launch_bounds__(256) void k_gemm2(
    const _Float16* __restrict__ A, const _Float16* __restrict__ Bt,
    const float* __restrict__ bias, void* __restrict__ Cout,
    int M, int N, int K, int nbx)
{
    constexpr int BUFSZ = 16384 + TNB * 128;
    __shared__ char sm[2 * BUFSZ];
    const int nwg = gridDim.x;
    const int bid = blockIdx.x;
    const int sw = (bid & 7) * (nwg >> 3) + (bid >> 3);   // XCD-chunked (nwg % 8 == 0)
    const int bx = sw % nbx, by = sw / nbx;
    const int m0 = by << 7, n0 = bx * TNB;
    const int tid = threadIdx.x;
    const int lane = tid & 63, l15 = lane & 15, g = lane >> 4;
    const int w = tid >> 6;
    constexpr int AM = (TNB == 128) ? 4 : 2;
    const int wm = (TNB == 128) ? ((w >> 1) << 6) : (w << 5);
    const int wn = (TNB == 128) ? ((w & 1) << 6) : 0;

    f32x4 acc[AM][4] = {};

    auto stage = [&](int kt, int bufsel) {
        char* As = sm + bufsel * BUFSZ;
        char* Bs = As + 16384;
        const char* Ag = (const char*)A + ((size_t)m0 * K + (kt << 6)) * 2;
#pragma unroll
        for (int i2 = 0; i2 < 4; ++i2) {
            int byte = (i2 << 12) + (tid << 4);
            int row = byte >> 7, bso = byte & 127;
            gll16(Ag + (size_t)row * (K * 2) + (bso ^ ((row & 7) << 4)), As + byte);
        }
        const char* Bg = (const char*)Bt + ((size_t)n0 * K + (kt << 6)) * 2;
#pragma unroll
        for (int i2 = 0; i2 < (TNB >> 5); ++i2) {
            int byte = (i2 << 12) + (tid << 4);
            int row = byte >> 7, bso = byte & 127;
            gll16(Bg + (size_t)row * (K * 2) + (bso ^ ((row & 7) << 4)), Bs + byte);
        }
    };

    const int nk = K >> 6;
    stage(0, 0);
    __syncthreads();
    for (int kt = 0; kt < nk; ++kt) {
        const int cur = kt & 1;
        if (kt + 1 < nk) stage(kt + 1, cur ^ 1);
        const char* As = sm + cur * BUFSZ;
        const char* Bs = As + 16384;
#pragma unroll
        for (int kq = 0; kq < 2; ++kq) {
            half8 af[AM], bf[4];
#pragma unroll
            for (int a = 0; a < AM; ++a) {
                int row = wm + (a << 4) + l15;
                af[a] = *(const half8*)(As + (row << 7) + ((((kq << 2) | g) ^ (row & 7)) << 4));
            }
#pragma unroll
            for (int bj = 0; bj < 4; ++bj) {
                int row = wn + (bj << 4) + l15;
                bf[bj] = *(const half8*)(Bs + (row << 7) + ((((kq << 2) | g) ^ (row & 7)) << 4));
            }
#pragma unroll
            for (int a = 0; a < AM; ++a)
#pragma unroll
                for (int bj = 0; bj < 4; ++bj)
                    acc[a][bj] = __builtin_amdgcn_mfma_f32_16x16x32_f16(af[a], bf[bj], acc[a][bj], 0, 0, 0);
        }
        __syncthreads();
    }
#pragma unroll
    for (int a = 0; a < AM; ++a)
#pragma unroll
        for (int bj = 0; bj < 4; ++bj)
#pragma unroll
            for (int r = 0; r < 4; ++r) {
                int row = m0 + wm + (a << 4) + (g << 2) + r;
                int col = n0 + wn + (bj << 4) + l15;
                float vv = acc[a][bj][r] + (bias ? bias[col] : 0.0f);
                if (OUT_F16) ((_Float16*)Cout)[(size_t)row * N + col] = (_Float16)vv;
                else         ((float*)Cout)[(size_t)row * N + col] = vv;
            }
}

// ---------------- QVh[(bh)*1024+i][k] = f16(Qh + v_h), half8 per thread ----------------
__global__ void k_qvh(const _Float16* __restrict__ Qh, const float* __restrict__ v,
                      _Float16* __restrict__ QVh) {
    int t = blockIdx.x * 256 + threadIdx.x;     // 262144 threads
    int k8 = (t & 7) << 3, r = t >> 3;
    int i = r & 1023, h = (r >> 10) & 7, b = r >> 13;
    half8 q = *(const half8*)(Qh + ((size_t)(b << 10) + i) * 2560 + (h << 6) + k8);
    float4 v0 = *(const float4*)(v + (h << 6) + k8);
    float4 v1 = *(const float4*)(v + (h << 6) + k8 + 4);
    float vv[8] = {v0.x, v0.y, v0.z, v0.w, v1.x, v1.y, v1.z, v1.w};
    half8 o;
#pragma unroll
    for (int z = 0; z < 8; ++z) o[z] = (_Float16)((float)q[z] + vv[z]);
    ((half8*)QVh)[t] = o;
}

// ---------------- Qext build: LOG2E * [Q(64) | A'_sin(96) | A'_cos(96)], SWIZZLED ----------------
__global__ void k_qext(const _Float16* __restrict__ Qh, const _Float16* __restrict__ Gf,
                       const float* __restrict__ Tsin, const float* __restrict__ Tcos,
                       _Float16* __restrict__ Qext) {
    int t = threadIdx.x;
    int r = (blockIdx.x << 3) + (t >> 5);
    int cc = t & 31;
    int i = r & 1023, h = (r >> 10) & 7, b = r >> 13;
    half8 val;
    if (cc < 8) {
        half8 q = *(const half8*)(Qh + ((size_t)(b << 10) + i) * 2560 + (h << 6) + (cc << 3));
#pragma unroll
        for (int z = 0; z < 8; ++z) val[z] = (_Float16)((float)q[z] * LOG2E_);
    } else {
        int f = (cc < 20) ? ((cc - 8) << 3) : ((cc - 20) << 3);
        half8 g0 = *(const half8*)(Gf + (size_t)r * 192 + f);
        half8 g1 = *(const half8*)(Gf + (size_t)r * 192 + 96 + f);
        float4 s0 = *(const float4*)(Tsin + i * 96 + f);
        float4 s1 = *(const float4*)(Tsin + i * 96 + f + 4);
        float4 c0 = *(const float4*)(Tcos + i * 96 + f);
        float4 c1 = *(const float4*)(Tcos + i * 96 + f + 4);
        float sv[8] = {s0.x, s0.y, s0.z, s0.w, s1.x, s1.y, s1.z, s1.w};
        float cv[8] = {c0.x, c0.y, c0.z, c0.w, c1.x, c1.y, c1.z, c1.w};
        if (cc < 20) {
#pragma unroll
            for (int z = 0; z < 8; ++z) val[z] = (_Float16)(((float)g0[z] * cv[z] + (float)g1[z] * sv[z]) * LOG2E_);
        } else {
#pragma unroll
            for (int z = 0; z < 8; ++z) val[z] = (_Float16)(((float)g1[z] * cv[z] - (float)g0[z] * sv[z]) * LOG2E_);
        }
    }
    *(half8*)((char*)Qext + (size_t)r * 512 + ((cc ^ (r & 7)) << 4)) = val;
}

// ---------------- Kext build + bias3 = LOG2E * (u_h . K_j), SWIZZLED ----------------
__global__ void k_kext(const _Float16* __restrict__ Kh, const float* __restrict__ u,
                       const float* __restrict__ Tsin, const float* __restrict__ Tcos,
                       _Float16* __restrict__ Kext, float* __restrict__ bias3) {
    int t = threadIdx.x;
    int r = (blockIdx.x << 3) + (t >> 5);
    int cc = t & 31;
    int j = r & 1023, h = (r >> 10) & 7, b = r >> 13;
    half8 val;
    if (cc < 8) {
        val = *(const half8*)(Kh + ((size_t)(b << 10) + j) * 2560 + 512 + (h << 6) + (cc << 3));
        float4 u0 = *(const float4*)(u + (h << 6) + (cc << 3));
        float4 u1 = *(const float4*)(u + (h << 6) + (cc << 3) + 4);
        float p = (float)val[0] * u0.x + (float)val[1] * u0.y + (float)val[2] * u0.z + (float)val[3] * u0.w
                + (float)val[4] * u1.x + (float)val[5] * u1.y + (float)val[6] * u1.z + (float)val[7] * u1.w;
        p += __shfl_xor(p, 1); p += __shfl_xor(p, 2); p += __shfl_xor(p, 4);
        if (cc == 0) bias3[r] = p * LOG2E_;
    } else {
        int f = (cc < 20) ? ((cc - 8) << 3) : ((cc - 20) << 3);
        const float* T = (cc < 20) ? Tsin : Tcos;
        float4 t0 = *(const float4*)(T + j * 96 + f);
        float4 t1 = *(const float4*)(T + j * 96 + f + 4);
        float tv[8] = {t0.x, t0.y, t0.z, t0.w, t1.x, t1.y, t1.z, t1.w};
#pragma unroll
        for (int z = 0; z < 8; ++z) val[z] = (_Float16)tv[z];
    }
    *(half8*)((char*)Kext + (size_t)r * 512 + ((cc ^ (r & 7)) << 4)) = val;
}

// ---------------- V pack: Vh -> Vd[(bh*192+d)*1024 + j] f16, per-64j 128B-chunk swizzle ----------------
__global__ void k_pack_v(const _Float16* __restrict__ Vh, _Float16* __restrict__ Vd) {
    __shared__ float tile[64][65];
    int j0 = blockIdx.x << 6, d0 = blockIdx.y << 6, bh = blockIdx.z;
    int b = bh >> 3, h = bh & 7;
    int tid = threadIdx.x;
#pragma unroll
    for (int q = 0; q < 16; ++q) {
        int e = (q << 8) + tid;
        int r = e >> 6, c = e & 63;
        tile[r][c] = (float)Vh[((size_t)(b << 10) + j0 + r) * 2560 + 1024 + h * 192 + d0 + c];
    }
    __syncthreads();
#pragma unroll
    for (int q = 0; q < 2; ++q) {
        int e = (q << 8) + tid;
        int dr = e >> 3, jc = e & 7;     // dr = d offset 0..63, jc = 16B chunk (8 j)
        half8 v;
#pragma unroll
        for (int z = 0; z < 8; ++z) v[z] = (_Float16)tile[(jc << 3) + z][dr];
        *(half8*)((char*)Vd + (((size_t)bh * 192 + d0 + dr) * 1024 + j0) * 2 + ((jc ^ (dr & 7)) << 4)) = v;
    }
}

// ---------------- fused rel-pos flash attention v9 ----------------
// a=1 waves sized to fit the 512-thread 128-VGPR cap WITHOUT spilling:
// per-wave live state = qf 32 + s 8 + oacc 48 + m/l 8 + addr ~25 ≈ 120 <= 128.
// 8 waves/block (forced 2 waves/SIMD co-residency) = 4 row-groups (16 q-rows)
// x 2 j-halves; block = 64 q-rows; grid 512 (XCD-chunked, 4 bh/XCD -> L2-
// resident K/V, proven 22.7MB fetch in R7). KVBLK=64 double-buffered.
// bias3 folded into accumulator init; defer-max softmax in exp2 domain.
__global__ __launch_bounds__(512, 1) void k_attn(
    const _Float16* __restrict__ Qext, const _Float16* __restrict__ Kext,
    const _Float16* __restrict__ Vd, const float* __restrict__ bias3,
    _Float16* __restrict__ AOh)
{
    __shared__ char smem[122880];   // K0@0 K1@32K V0@64K V1@88K P@112K+w*1K

    const int bid = blockIdx.x;
    const int sw = ((bid & 7) << 6) + (bid >> 3);   // 64 blocks per XCD chunk
    const int bh = sw >> 4;
    const int i0 = (sw & 15) << 6;                  // 64 q-rows per block
    const int tid = threadIdx.x;
    const int w = tid >> 6, lane = tid & 63, l15 = lane & 15, g = lane >> 4;
    const int rowg = w & 3, jhalf = w >> 2;
    const int b = bh >> 3, h = bh & 7;

    const char* Kg = (const char*)Kext + ((size_t)bh << 10) * 512;
    const char* Vg = (const char*)Vd + (size_t)bh * 192 * 2048;
    const float* b3g = bias3 + (bh << 10);
    char* Pw = smem + 114688 + (w << 10);

    // Q fragments (swizzled global layout): rows i0 + rowg*16 + l15
    half8 qf[8];
    {
        int row = i0 + (rowg << 4) + l15;
        const char* qp = (const char*)Qext + ((size_t)(bh << 10) + row) * 512;
#pragma unroll
        for (int kq = 0; kq < 8; ++kq)
            qf[kq] = *(const half8*)(qp + ((((kq << 2) + g) ^ (row & 7)) << 4));
    }

    f32x4 oacc[12] = {};
    float m_run[4], l_lane[4];
#pragma unroll
    for (int r = 0; r < 4; ++r) { m_run[r] = -3.0e38f; l_lane[r] = 0.f; }

    auto stage = [&](int jt, int bufsel) {
        char* Kb = smem + bufsel * 32768;
        char* Vb = smem + 65536 + bufsel * 24576;
        const char* Ksrc = Kg + (size_t)jt * 32768;
#pragma unroll
        for (int i2 = 0; i2 < 4; ++i2) {
            int byte = (i2 << 13) + (tid << 4);
            gll16(Ksrc + byte, Kb + byte);
        }
#pragma unroll
        for (int i2 = 0; i2 < 3; ++i2) {
            int byte = (i2 << 13) + (tid << 4);
            int d = byte >> 7, c = byte & 127;
            gll16(Vg + (size_t)d * 2048 + (jt << 7) + c, Vb + byte);
        }
    };

    stage(0, 0);
    __syncthreads();

    for (int jt = 0; jt < 16; ++jt) {
        const int cur = jt & 1;
        if (jt + 1 < 16) stage(jt + 1, cur ^ 1);
        const char* Kb = smem + cur * 32768;
        const char* Vb = smem + 65536 + cur * 24576;

        // S = Qext @ Kext^T : 1 row-frag x 2 col-frags (wave's 32-col j-half)
        // term3 bias folded into accumulator init (per j column = l15 lane)
        f32x4 s[2];
#pragma unroll
        for (int jn = 0; jn < 2; ++jn) {
            float b3 = b3g[(jt << 6) + (jhalf << 5) + (jn << 4) + l15];
            s[jn] = (f32x4){b3, b3, b3, b3};
        }
        __builtin_amdgcn_s_setprio(1);
#pragma unroll
        for (int kq = 0; kq < 8; ++kq) {
#pragma unroll
            for (int jn = 0; jn < 2; ++jn) {
                int krow = (((jhalf << 1) + jn) << 4) + l15;
                half8 bf = *(const half8*)(Kb + (krow << 9) + ((((kq << 2) + g) ^ (krow & 7)) << 4));
                s[jn] = __builtin_amdgcn_mfma_f32_16x16x32_f16(qf[kq], bf, s[jn], 0, 0, 0);
            }
        }
        __builtin_amdgcn_s_setprio(0);
        // defer-max online softmax (log2 domain)
        bool pass = true;
#pragma unroll
        for (int jn = 0; jn < 2; ++jn)
#pragma unroll
            for (int r = 0; r < 4; ++r) pass &= (s[jn][r] <= m_run[r] + 8.0f);
        if (!__all(pass)) {
#pragma unroll
            for (int r = 0; r < 4; ++r) {
                float tm = fmaxf(s[0][r], s[1][r]);
                tm = fmaxf(tm, __shfl_xor(tm, 1));
                tm = fmaxf(tm, __shfl_xor(tm, 2));
                tm = fmaxf(tm, __shfl_xor(tm, 4));
                tm = fmaxf(tm, __shfl_xor(tm, 8));
                float mnew = fmaxf(m_run[r], tm);
                float al = exp2f(m_run[r] - mnew);
                l_lane[r] *= al;
                m_run[r] = mnew;
#pragma unroll
                for (int dn = 0; dn < 12; ++dn) oacc[dn][r] *= al;
            }
        }
        // P = exp2(s-m) -> wave-private LDS [16 rows][64B], chunk swz c^=(row>>2)&3
#pragma unroll
        for (int jn = 0; jn < 2; ++jn)
#pragma unroll
            for (int r = 0; r < 4; ++r) {
                float p = exp2f(s[jn][r] - m_run[r]);
                l_lane[r] += p;
                int row = (g << 2) + r;
                int c = ((jn << 1) + (l15 >> 3)) ^ g;
                *(_Float16*)(Pw + (row << 6) + (c << 4) + ((l15 & 7) << 1)) = (_Float16)p;
            }
        // P A-frag back (same wave): row = l15, 8 j at g*8
        half8 pa;
        {
            int c = g ^ ((l15 >> 2) & 3);
            pa = *(const half8*)(Pw + (l15 << 6) + (c << 4));
        }
        // O += P @ V  (16x16x32, inner = wave's 32 j)
        __builtin_amdgcn_s_setprio(1);
#pragma unroll
        for (int dn = 0; dn < 12; ++dn) {
            int d = (dn << 4) + l15;
            half8 vb = *(const half8*)(Vb + (d << 7) + ((((jhalf << 2) + g) ^ (d & 7)) << 4));
            oacc[dn] = __builtin_amdgcn_mfma_f32_16x16x32_f16(pa, vb, oacc[dn], 0, 0, 0);
        }
        __builtin_amdgcn_s_setprio(0);
        __syncthreads();
    }

    // reduce l across the 16 j-lanes (per row)
    float l_run[4];
#pragma unroll
    for (int r = 0; r < 4; ++r) {
        float l = l_lane[r];
        l += __shfl_xor(l, 1);
        l += __shfl_xor(l, 2);
        l += __shfl_xor(l, 4);
        l += __shfl_xor(l, 8);
        l_run[r] = l;
    }

    // ---- combine the two j-halves ----
    float* Cml = (float*)smem;             // [2 jhalf][64 rows][m,l]
    float* Co  = (float*)(smem + 2048);    // [64][196] f32 partial O
#pragma unroll
    for (int r = 0; r < 4; ++r)
        if (l15 == 0) {
            int rowi = (rowg << 4) + (g << 2) + r;
            Cml[(((jhalf << 6) + rowi) << 1) + 0] = m_run[r];
            Cml[(((jhalf << 6) + rowi) << 1) + 1] = l_run[r];
        }
    __syncthreads();
    float fs[4], lt[4];
#pragma unroll
    for (int r = 0; r < 4; ++r) {
        int rowi = (rowg << 4) + (g << 2) + r;
        float mo = Cml[((((1 - jhalf) << 6) + rowi) << 1) + 0];
        float lo = Cml[((((1 - jhalf) << 6) + rowi) << 1) + 1];
        float M = fmaxf(m_run[r], mo);
        float f0 = exp2f(m_run[r] - M);
        float f1 = exp2f(mo - M);
        fs[r] = f0;
        lt[r] = l_run[r] * f0 + lo * f1;
    }
    if (jhalf == 1) {
#pragma unroll
        for (int dn = 0; dn < 12; ++dn)
#pragma unroll
            for (int r = 0; r < 4; ++r) {
                int rowi = (rowg << 4) + (g << 2) + r;
                Co[rowi * 196 + (dn << 4) + l15] = oacc[dn][r] * fs[r];
            }
    }
    __syncthreads();
    if (jhalf == 0) {
#pragma unroll
        for (int r = 0; r < 4; ++r) {
            int rowi = (rowg << 4) + (g << 2) + r;
            float inv = 1.0f / lt[r];
#pragma unroll
            for (int dn = 0; dn < 12; ++dn) {
                float ov = (oacc[dn][r] * fs[r] + Co[rowi * 196 + (dn << 4) + l15]) * inv;
                AOh[((size_t)(b << 10) + i0 + rowi) * 1536 + h * 192 + (dn << 4) + l15] = (_Float16)ov;
            }
        }
    }
}

// ---------------- host launch ----------------
extern "C" void kernel_launch(void* const* d_in, const int* in_sizes, int n_in,
                              void* d_out, int out_size, void* d_ws, size_t ws_size,
                              hipStream_t stream) {
    const float* x  = (const float*)d_in[0];
    const float* Wq = (const float*)d_in[1];
    const float* bq = (const float*)d_in[2];
    const float* Wk = (const float*)d_in[3];
    const float* bk = (const float*)d_in[4];
    const float* Wv = (const float*)d_in[5];
    const float* bv = (const float*)d_in[6];
    const float* Wo = (const float*)d_in[7];
    const float* bo = (const float*)d_in[8];
    const float* We = (const float*)d_in[9];
    const float* u  = (const float*)d_in[10];
    const float* v  = (const float*)d_in[11];
    float* out = (float*)d_out;

    char* ws = (char*)d_ws;
    size_t off = 0;
    auto alloc = [&](size_t bytes) -> void* {
        void* p = ws + off;
        off += (bytes + 255) & ~(size_t)255;
        return p;
    };
    _Float16* xh    = (_Float16*)alloc((size_t)4096 * 512 * 2);
    _Float16* Weh   = (_Float16*)alloc((size_t)192 * 64 * 2);
    _Float16* Wqkvt = (_Float16*)alloc((size_t)2560 * 512 * 2);
    _Float16* Wot   = (_Float16*)alloc((size_t)512 * 1536 * 2);
    float*    bqkv  = (float*)alloc((size_t)2560 * 4);
    float*    Tsin  = (float*)alloc((size_t)1024 * 96 * 4);
    float*    Tcos  = (float*)alloc((size_t)1024 * 96 * 4);
    _Float16* QKVh  = (_Float16*)alloc((size_t)4096 * 2560 * 2);
    _Float16* QVh   = (_Float16*)alloc((size_t)32768 * 64 * 2);
    _Float16* Gf16  = (_Float16*)alloc((size_t)32768 * 192 * 2);
    _Float16* Qext  = (_Float16*)alloc((size_t)32768 * 256 * 2);
    _Float16* Kext  = (_Float16*)alloc((size_t)32768 * 256 * 2);
    float*    bias3 = (float*)alloc((size_t)32768 * 4);
    _Float16* Vd    = (_Float16*)alloc((size_t)32 * 192 * 1024 * 2);
    _Float16* AOh   = (_Float16*)alloc((size_t)4096 * 1536 * 2);
    if (off > ws_size) return;  // insufficient workspace -> clean fail

    // converts / transposes / tables
    k_f32_to_f16<<<2048, 256, 0, stream>>>(x, xh, 4096 * 512 / 4);
    k_f32_to_f16<<<12, 256, 0, stream>>>(We, Weh, 192 * 64 / 4);
    k_transpose_f16<<<dim3(8, 8), 256, 0, stream>>>(Wq, Wqkvt, 512, 512);
    k_transpose_f16<<<dim3(8, 8), 256, 0, stream>>>(Wk, Wqkvt + (size_t)512 * 512, 512, 512);
    k_transpose_f16<<<dim3(24, 8), 256, 0, stream>>>(Wv, Wqkvt + (size_t)1024 * 512, 512, 1536);
    k_transpose_f16<<<dim3(8, 24), 256, 0, stream>>>(Wo, Wot, 1536, 512);
    k_concat_bias<<<10, 256, 0, stream>>>(bq, bk, bv, bqkv);
    k_trig<<<(1024 * 96 + 255) / 256, 256, 0, stream>>>(Tsin, Tcos);

    // fused QKV projection (f16 out): [4096,2560] = xh @ Wqkvt^T + bqkv
    k_gemm2<128, true><<<640, 256, 0, stream>>>(xh, Wqkvt, bqkv, QKVh, 4096, 2560, 512, 20);

    // G = (Q + v_h) @ We^T  (f16 out)
    k_qvh<<<1024, 256, 0, stream>>>(QKVh, v, QVh);
    k_gemm2<64, true><<<768, 256, 0, stream>>>(QVh, Weh, nullptr, Gf16, 32768, 192, 64, 3);

    // extended Q / K (swizzled, LOG2E-folded) + column bias; V pack (swizzled)
    k_qext<<<4096, 256, 0, stream>>>(QKVh, Gf16, Tsin, Tcos, Qext);
    k_kext<<<4096, 256, 0, stream>>>(QKVh, u, Tsin, Tcos, Kext, bias3);
    k_pack_v<<<dim3(16, 3, 32), 256, 0, stream>>>(QKVh, Vd);

    // fused attention
    k_attn<<<512, 512, 0, stream>>>(Qext, Kext, Vd, bias3, AOh);

    // output projection -> d_out (f32)
    k_gemm2<64, false><<<256, 256, 0, stream>>>(AOh, Wot, bo, out, 4096, 512, 1536, 8);
}